// Round 7
// baseline (145.765 us; speedup 1.0000x reference)
//
#include <hip/hip_runtime.h>

// SlidingKernelAttention: unfold(k=4,s=1) -> per-(b,c,patch-offset) attention
// over seq=256 tokens of dim=16 -> overlap-add fold.
// B=2, C=64, H=W=67, Ho=Wo=64, N = B*C*16 = 2048 independent sequences.
//
// R16: FULLY FUSED single kernel. Six consecutive nulls (R8-R15) failed to
// dent the two-pass structure's fixed ~25us overhead; this abandons the
// structure. Block = bc (grid 128, 1024 thr = 16 waves), one wave per
// plane-sequence p=(i,j). The fold is block-private: plane (i,j)
// contributes ao[h'][w'] to out[h'+i][w'+j] with h',w' in [0,64) and
// 64+3=67, so a 67x68 f32 LDS tile receives every contribution for this
// bc with no bounds checks, then plain coalesced stores. Deleted: the
// 16.8MB ao write + read, pass2, the d_ws dependency, all KV LDS staging
// (fragments live in wave-private registers, fully unrolled static
// indexing), and all barriers except {after LDS zero, before store}.
// ao stays f32 end-to-end (more accurate than the old f16 workspace).
//
// Per wave: X direct-to-register (R13 addressing; x[bc] = 18KB -> L1),
// projection kf/vf/qf[16] (48 MFMAs, ~96 VGPR), then the R11 2-q-tile
// main loop (jq unrolled x8, t x16), shfl_xor denom reduce, 4x
// ds atomicAdd (f32) into the fold tile per q-tile.
//
// MFMA layout identity (R5-R8): 16x16 MFMA C/D layout == A-operand layout
// == B-operand layout, so projection MFMA results ARE attention operands:
//   K^T = Wk.X^T    -> A-frag of K      (for S^T = K.Q^T)
//   V   = X.Wv^T    -> A-frag of V^T    (for O^T = V^T.P^T)
//   Q^T = s.Wq.X^T  -> B-frag of Q^T
//   P^T = exp2(S^T) -> B-frag of P^T    (in-register)
// Fold mapping (verified against the reference reshape): feature d of
// token q of plane (i,j) sits at plane pos h'=(q>>2... wait, derived:
//   h' = 4*jq + (o>>2), w' = 16*(o&3) + 4g + idx  -> out[h'+i][w'+j].
// All fragments statically indexed (R4 lesson: dynamic reg-array indexing
// -> scratch lowering). f16 vectors via v_cvt_pkrtz + bit_cast /
// shufflevector only (R8).
// Timed window still includes the ~43-50us harness fill of the (now
// unused) 268MB d_ws; read deltas as total minus the per-run fill dur.

#define BATCH 2
#define CHAN 64
#define HWDIM 67
#define SEQ 256
#define DIM 16
#define ATT_SCALE 0.70710678118654752f             // (DIM/HEADS)^-0.5
#define LOG2E 1.44269504088896340736f

typedef _Float16 half4 __attribute__((ext_vector_type(4)));
typedef _Float16 half8 __attribute__((ext_vector_type(8)));
typedef float float4v __attribute__((ext_vector_type(4)));
typedef __fp16 fp16x2 __attribute__((ext_vector_type(2)));
typedef unsigned int uint2v __attribute__((ext_vector_type(2)));

// 2x v_cvt_pkrtz + register-pair aliasing: zero insert/extract VALU.
static __device__ __forceinline__ half4 mk_half4(float a, float b, float c, float d) {
    fp16x2 lo = __builtin_amdgcn_cvt_pkrtz(a, b);
    fp16x2 hi = __builtin_amdgcn_cvt_pkrtz(c, d);
    uint2v u;
    u[0] = __builtin_bit_cast(unsigned int, lo);
    u[1] = __builtin_bit_cast(unsigned int, hi);
    return __builtin_bit_cast(half4, u);
}

static __device__ __forceinline__ half4 pack4(float4v c) {
    return mk_half4(c[0], c[1], c[2], c[3]);
}

// one q-tile step: exp2 the 4 scores, accumulate denominator, pack,
// accumulate O^T.
static __device__ __forceinline__ void att_step(const half4 vf, const float4v sfr,
                                                float& l, float4v& oacc) {
    const float p0 = __builtin_amdgcn_exp2f(sfr[0]);
    const float p1 = __builtin_amdgcn_exp2f(sfr[1]);
    const float p2 = __builtin_amdgcn_exp2f(sfr[2]);
    const float p3 = __builtin_amdgcn_exp2f(sfr[3]);
    l += (p0 + p1) + (p2 + p3);
    const half4 pb = mk_half4(p0, p1, p2, p3);
    oacc = __builtin_amdgcn_mfma_f32_16x16x16f16(vf, pb, oacc, 0, 0, 0);
}

__global__ __launch_bounds__(1024, 1) void ska_fused(
    const float* __restrict__ x,      // [B, C, 67, 67]
    const float* __restrict__ w,      // [48, 16]
    float* __restrict__ out)          // [B, C, 67, 67]
{
    // block-private overlap-add accumulator for this bc (pad col: 68)
    __shared__ float fold[HWDIM][68];   // 18.2 KB

    const int bc  = blockIdx.x;
    const int tid = threadIdx.x;

    // zero the fold tile (barrier below, before any atomicAdd)
    {
        float* ff = &fold[0][0];
        for (int i = tid; i < HWDIM * 68; i += 1024) ff[i] = 0.f;
    }

    const int wv   = tid >> 6;     // wave = plane p = 0..15
    const int ii   = wv >> 2;      // patch-row offset i
    const int jj   = wv & 3;       // patch-col offset j
    const int lane = tid & 63;
    const int o = lane & 15;       // token-in-tile / weight output row
    const int g = lane >> 4;       // feature group (k-group)

    // weight fragments straight from global (3 KB, L1-resident)
    const float4 wq4 = *(const float4*)(w + ( 0 + o) * DIM + 4 * g);
    const float4 wk4 = *(const float4*)(w + (16 + o) * DIM + 4 * g);
    const float4 wv4 = *(const float4*)(w + (32 + o) * DIM + 4 * g);
    const half4 wqf = mk_half4(wq4.x * (ATT_SCALE * LOG2E), wq4.y * (ATT_SCALE * LOG2E),
                               wq4.z * (ATT_SCALE * LOG2E), wq4.w * (ATT_SCALE * LOG2E));
    const half4 wkf = mk_half4(wk4.x, wk4.y, wk4.z, wk4.w);
    const half4 wvf = mk_half4(wv4.x, wv4.y, wv4.z, wv4.w);

    const float4v zf = (float4v){0.f, 0.f, 0.f, 0.f};

    // X direct-to-register + projection into wave-private fragment file.
    // Lane (o,g) of tile t holds features 4g..4g+3 of token s=t*16+o:
    //   x[bc][4t + (o>>2) + ii][16*(o&3) + 4g + jj .. +3]
    // x[bc] is 18 KB -> L1-resident across the 16 waves.
    const float* xb = x + ((size_t)bc * HWDIM + ii) * HWDIM + (o & 3) * 16 + 4 * g + jj;
    half4 kf[16], vf[16], qf[16];
#pragma unroll
    for (int t = 0; t < 16; ++t) {
        const float* xp = xb + (4 * t + (o >> 2)) * HWDIM;
        const half4 xf = mk_half4(xp[0], xp[1], xp[2], xp[3]);
        kf[t] = pack4(__builtin_amdgcn_mfma_f32_16x16x16f16(wkf, xf, zf, 0, 0, 0));
        vf[t] = pack4(__builtin_amdgcn_mfma_f32_16x16x16f16(xf, wvf, zf, 0, 0, 0));
        qf[t] = pack4(__builtin_amdgcn_mfma_f32_16x16x16f16(wqf, xf, zf, 0, 0, 0));
    }

    __syncthreads();   // fold tile zeroed; waves now run independently

    // attention: 2 q-tiles per step (ILP pair, as R11), fully unrolled so
    // every kf/vf/qf access is a static register index.
#pragma unroll
    for (int jq = 0; jq < 16; jq += 2) {
        float4v oacc0 = zf, oacc1 = zf;
        float l0 = 0.f, l1 = 0.f;
#pragma unroll
        for (int t = 0; t < 16; ++t) {
            const float4v s0 = __builtin_amdgcn_mfma_f32_16x16x16f16(kf[t], qf[jq],     zf, 0, 0, 0);
            const float4v s1 = __builtin_amdgcn_mfma_f32_16x16x16f16(kf[t], qf[jq + 1], zf, 0, 0, 0);
            att_step(vf[t], s0, l0, oacc0);
            att_step(vf[t], s1, l1, oacc1);
        }
        // denominator reduce + fold the two finished q-tiles into LDS
#pragma unroll
        for (int u = 0; u < 2; ++u) {
            float lj = u ? l1 : l0;
            lj += __shfl_xor(lj, 16, 64);
            lj += __shfl_xor(lj, 32, 64);
            const float rl = __builtin_amdgcn_rcpf(lj);
            const float4v oa = u ? oacc1 : oacc0;
            const int r = 4 * (jq + u) + (o >> 2) + ii;       // out row
            const int c = 16 * (o & 3) + 4 * g + jj;          // out col base
            atomicAdd(&fold[r][c + 0], oa[0] * rl);
            atomicAdd(&fold[r][c + 1], oa[1] * rl);
            atomicAdd(&fold[r][c + 2], oa[2] * rl);
            atomicAdd(&fold[r][c + 3], oa[3] * rl);
        }
    }

    __syncthreads();   // all 16 planes folded

    // coalesced store of the completed 67x67 tile
    float* ob = out + (size_t)bc * (HWDIM * HWDIM);
    for (int pix = tid; pix < HWDIM * HWDIM; pix += 1024) {
        ob[pix] = fold[pix / HWDIM][pix % HWDIM];
    }
}

extern "C" void kernel_launch(void* const* d_in, const int* in_sizes, int n_in,
                              void* d_out, int out_size, void* d_ws, size_t ws_size,
                              hipStream_t stream) {
    const float* x = (const float*)d_in[0];
    const float* w = (const float*)d_in[1];
    float* out = (float*)d_out;
    (void)d_ws; (void)ws_size; (void)in_sizes; (void)n_in; (void)out_size;

    ska_fused<<<BATCH * CHAN, 1024, 0, stream>>>(x, w, out);
}

// Round 8
// 80.794 us; speedup vs baseline: 1.8042x; 1.8042x over previous
//
#include <hip/hip_runtime.h>

// SlidingKernelAttention: unfold(k=4,s=1) -> per-(b,c,patch-offset) attention
// over seq=256 tokens of dim=16 -> overlap-add fold.
// B=2, C=64, H=W=67, Ho=Wo=64, N = B*C*16 = 2048 independent sequences.
//
// R17 = R16's fusion with R11/R15's low-register engine. R16 post-mortem:
// VGPR_Count=64 vs ~96 needed for the whole-sequence-per-wave KV file ->
// full scratch spill (95us, VALUBusy 14.9%, MfmaUtil 7.4%, HBM 0.5% = the
// scratch-latency signature; rule #20). Also learned the ~47us d_ws fill
// runs even when d_ws is unused -> unavoidable fixed overhead in the
// timed window; floor = fill + kernel.
//
// Structure: block = (bc, ii), 512 blocks x 512 thr (2 blocks/CU, 16
// waves/CU = 4/SIMD, all 256 CUs busy). Each block processes its 4 planes
// (jj=0..3) serially: R15 cross-plane x-prefetch into registers ->
// projection (3 MFMA/tile) -> KV frags to double-buffered LDS (2x16KB) ->
// one barrier -> R11 main loop (2 q-tiles/wave, 16 k-tiles) -> wave-
// private fold. Fold rows r = 4*jq+(o>>2) lie in [8*wave, 8*wave+8) ->
// fold tile needs NO atomics (plain +=). Blocks of one bc overlap out
// rows -> out pre-zeroed (hipMemsetAsync, ~0.6us) + global atomicAdd
// merge (4288/block). LDS = 32KB KV + 64x69 f32 fold (17.6KB) = 49.6KB.
// Registers ~= R11's engine (~50): qfr[2], kv prefetch, oacc[2], weights.
//
// MFMA layout identity (R5-R8): 16x16 MFMA C/D layout == A-operand layout
// == B-operand layout, so projection MFMA results ARE attention operands:
//   K^T = Wk.X^T    -> A-frag of K      (for S^T = K.Q^T)
//   V   = X.Wv^T    -> A-frag of V^T    (for O^T = V^T.P^T)
//   Q^T = s.Wq.X^T  -> B-frag of Q^T
//   P^T = exp2(S^T) -> B-frag of P^T    (in-register)
// Fold mapping (HW-verified in R16: absmax unchanged): feature idx of
// query q=jq*16+o of plane (ii,jj) adds to
//   out[bc][4*jq+(o>>2) + ii][16*(o&3)+4*g+idx + jj].
// All fragments statically indexed (R4); f16 vectors via v_cvt_pkrtz +
// bit_cast / shufflevector only (R8).
// Timed window includes the ~47us harness fill of the unused 268MB d_ws.

#define BATCH 2
#define CHAN 64
#define HWDIM 67
#define SEQ 256
#define DIM 16
#define OUT_TOTAL (BATCH * CHAN * HWDIM * HWDIM)   // 574592
#define ATT_SCALE 0.70710678118654752f             // (DIM/HEADS)^-0.5
#define LOG2E 1.44269504088896340736f

typedef _Float16 half4 __attribute__((ext_vector_type(4)));
typedef _Float16 half8 __attribute__((ext_vector_type(8)));
typedef float float4v __attribute__((ext_vector_type(4)));
typedef __fp16 fp16x2 __attribute__((ext_vector_type(2)));
typedef unsigned int uint2v __attribute__((ext_vector_type(2)));

// 2x v_cvt_pkrtz + register-pair aliasing: zero insert/extract VALU.
static __device__ __forceinline__ half4 mk_half4(float a, float b, float c, float d) {
    fp16x2 lo = __builtin_amdgcn_cvt_pkrtz(a, b);
    fp16x2 hi = __builtin_amdgcn_cvt_pkrtz(c, d);
    uint2v u;
    u[0] = __builtin_bit_cast(unsigned int, lo);
    u[1] = __builtin_bit_cast(unsigned int, hi);
    return __builtin_bit_cast(half4, u);
}

static __device__ __forceinline__ half4 pack4(float4v c) {
    return mk_half4(c[0], c[1], c[2], c[3]);
}

// one q-tile step: exp2 the 4 scores, accumulate denominator, pack,
// accumulate O^T.
static __device__ __forceinline__ void att_step(const half4 vf, const float4v sfr,
                                                float& l, float4v& oacc) {
    const float p0 = __builtin_amdgcn_exp2f(sfr[0]);
    const float p1 = __builtin_amdgcn_exp2f(sfr[1]);
    const float p2 = __builtin_amdgcn_exp2f(sfr[2]);
    const float p3 = __builtin_amdgcn_exp2f(sfr[3]);
    l += (p0 + p1) + (p2 + p3);
    const half4 pb = mk_half4(p0, p1, p2, p3);
    oacc = __builtin_amdgcn_mfma_f32_16x16x16f16(vf, pb, oacc, 0, 0, 0);
}

__global__ __launch_bounds__(512, 4) void ska_fused(
    const float* __restrict__ x,      // [B, C, 67, 67]
    const float* __restrict__ w,      // [48, 16]
    float* __restrict__ out)          // [B, C, 67, 67], pre-zeroed
{
    // KV double buffer (per plane) + block-private fold tile.
    // fold stride 69 (coprime with 32) to spread fold-RMW banks.
    __shared__ __align__(16) _Float16 buf[2][16][64][8];   // 32 KB
    __shared__ float fold[64][69];                          // 17.6 KB

    // XCD chunked swizzle: 512 blocks = 8 XCDs x 64 -> bc [16k,16k+16) on
    // XCD k; the 4 blocks of a bc share x[bc] (18KB) in one XCD's L2.
    const int b  = (int)(blockIdx.x & 7) * 64 + (int)(blockIdx.x >> 3);
    const int bc = b >> 2;
    const int ii = b & 3;          // patch-row offset of this block's planes

    const int tid  = threadIdx.x;
    const int wave = tid >> 6;     // 0..7: owns q/k tiles 2w, 2w+1
    const int lane = tid & 63;
    const int o = lane & 15;       // token-in-tile / weight output row
    const int g = lane >> 4;       // feature group (k-group)

    // zero the fold tile (first KV barrier below covers the hazard:
    // fold writes happen only after that barrier)
    {
        float* ff = &fold[0][0];
        for (int i = tid; i < 64 * 69; i += 512) ff[i] = 0.f;
    }

    // weight fragments straight from global (3 KB, L1-resident)
    const float4 wq4 = *(const float4*)(w + ( 0 + o) * DIM + 4 * g);
    const float4 wk4 = *(const float4*)(w + (16 + o) * DIM + 4 * g);
    const float4 wv4 = *(const float4*)(w + (32 + o) * DIM + 4 * g);
    const half4 wqf = mk_half4(wq4.x * (ATT_SCALE * LOG2E), wq4.y * (ATT_SCALE * LOG2E),
                               wq4.z * (ATT_SCALE * LOG2E), wq4.w * (ATT_SCALE * LOG2E));
    const half4 wkf = mk_half4(wk4.x, wk4.y, wk4.z, wk4.w);
    const half4 wvf = mk_half4(wv4.x, wv4.y, wv4.z, wv4.w);

    const float4v zf = (float4v){0.f, 0.f, 0.f, 0.f};

    // X addressing (R13/R15, HW-verified): lane (o,g) of tile t of plane
    // (ii,jj) holds features 4g..4g+3 of token s=t*16+o:
    //   x[bc][4t + (o>>2) + ii][16*(o&3) + 4g + jj .. +3]
    // Wave w owns tiles 2w, 2w+1 -> row offsets roff0/roff1.
    const float* xb = x + ((size_t)bc * HWDIM + ii) * HWDIM + (o & 3) * 16 + 4 * g;
    const int roff0 = (8 * wave + (o >> 2)) * HWDIM;
    const int roff1 = roff0 + 4 * HWDIM;

    // prefetch plane jj=0 (scalar loads; jj>0 addresses are 4B-aligned)
    float xr0a = xb[roff0 + 0], xr0b = xb[roff0 + 1],
          xr0c = xb[roff0 + 2], xr0d = xb[roff0 + 3];
    float xr1a = xb[roff1 + 0], xr1b = xb[roff1 + 1],
          xr1c = xb[roff1 + 2], xr1d = xb[roff1 + 3];

    for (int jj = 0; jj < 4; ++jj) {
        const int cur = jj & 1;

        // projection for plane jj from the prefetched x registers
        half4 qfr0, qfr1;
        {
            const half4 xf0 = mk_half4(xr0a, xr0b, xr0c, xr0d);
            const half4 kf0 = pack4(__builtin_amdgcn_mfma_f32_16x16x16f16(wkf, xf0, zf, 0, 0, 0));
            const half4 vf0 = pack4(__builtin_amdgcn_mfma_f32_16x16x16f16(xf0, wvf, zf, 0, 0, 0));
            *(half8*)&buf[cur][2 * wave][lane][0] =
                __builtin_shufflevector(kf0, vf0, 0, 1, 2, 3, 4, 5, 6, 7);
            qfr0 = pack4(__builtin_amdgcn_mfma_f32_16x16x16f16(wqf, xf0, zf, 0, 0, 0));

            const half4 xf1 = mk_half4(xr1a, xr1b, xr1c, xr1d);
            const half4 kf1 = pack4(__builtin_amdgcn_mfma_f32_16x16x16f16(wkf, xf1, zf, 0, 0, 0));
            const half4 vf1 = pack4(__builtin_amdgcn_mfma_f32_16x16x16f16(xf1, wvf, zf, 0, 0, 0));
            *(half8*)&buf[cur][2 * wave + 1][lane][0] =
                __builtin_shufflevector(kf1, vf1, 0, 1, 2, 3, 4, 5, 6, 7);
            qfr1 = pack4(__builtin_amdgcn_mfma_f32_16x16x16f16(wqf, xf1, zf, 0, 0, 0));
        }

        // issue next plane's x loads now (+1 column); consumed after this
        // plane's main loop -> latency hides under ~1.4us of compute.
        if (jj < 3) {
            const int d = jj + 1;
            xr0a = xb[roff0 + d + 0]; xr0b = xb[roff0 + d + 1];
            xr0c = xb[roff0 + d + 2]; xr0d = xb[roff0 + d + 3];
            xr1a = xb[roff1 + d + 0]; xr1b = xb[roff1 + d + 1];
            xr1c = xb[roff1 + d + 2]; xr1d = xb[roff1 + d + 3];
        }

        __syncthreads();   // kv frags of plane jj ready (one barrier/plane;
                           // also orders round-0 fold writes after zeroing)

        float4v oacc0 = zf, oacc1 = zf;
        float l0 = 0.f, l1 = 0.f;

        // main loop (R11, unchanged — trans/VALU floor per R12): one
        // ds_read_b128 per k-tile, prefetched one tile ahead; 2 S-MFMAs
        // issue before the exp2/pack/O-MFMA phase.
        half8 kvc = *(const half8*)&buf[cur][0][lane][0];
#pragma unroll 4
        for (int t = 0; t < 16; ++t) {
            const half8 kvn = *(const half8*)&buf[cur][(t + 1) & 15][lane][0];
            const half4 kf = __builtin_shufflevector(kvc, kvc, 0, 1, 2, 3);
            const half4 vf = __builtin_shufflevector(kvc, kvc, 4, 5, 6, 7);
            const float4v s0 = __builtin_amdgcn_mfma_f32_16x16x16f16(kf, qfr0, zf, 0, 0, 0);
            const float4v s1 = __builtin_amdgcn_mfma_f32_16x16x16f16(kf, qfr1, zf, 0, 0, 0);
            att_step(vf, s0, l0, oacc0);
            att_step(vf, s1, l1, oacc1);
            kvc = kvn;
        }

        // denom reduce + fold. Fold rows r = 4*(2w+u)+(o>>2) are in
        // [8*wave, 8*wave+8) -> wave-private -> plain += (no atomics).
#pragma unroll
        for (int u = 0; u < 2; ++u) {
            float lj = u ? l1 : l0;
            lj += __shfl_xor(lj, 16, 64);
            lj += __shfl_xor(lj, 32, 64);
            const float rl = __builtin_amdgcn_rcpf(lj);
            const float4v oa = u ? oacc1 : oacc0;
            const int r = 8 * wave + 4 * u + (o >> 2);
            const int c = 16 * (o & 3) + 4 * g + jj;
            fold[r][c + 0] += oa[0] * rl;
            fold[r][c + 1] += oa[1] * rl;
            fold[r][c + 2] += oa[2] * rl;
            fold[r][c + 3] += oa[3] * rl;
        }
        // no trailing barrier: next projection writes buf[(jj+1)&1];
        // buf[jj&1] is reused only after the NEXT barrier (hazard-free,
        // R15 analysis). fold rows are wave-private across rounds.
    }

    __syncthreads();   // all planes folded

    // merge this block's 64x67 partial into out (pre-zeroed; the 4 blocks
    // of a bc overlap rows -> atomicAdd, ~4288/block)
    float* ob = out + ((size_t)bc * HWDIM + ii) * HWDIM;
    for (int i = tid; i < 64 * HWDIM; i += 512) {
        const int r = i / HWDIM;
        const int c = i % HWDIM;
        atomicAdd(&ob[r * HWDIM + c], fold[r][c]);
    }
}

extern "C" void kernel_launch(void* const* d_in, const int* in_sizes, int n_in,
                              void* d_out, int out_size, void* d_ws, size_t ws_size,
                              hipStream_t stream) {
    const float* x = (const float*)d_in[0];
    const float* w = (const float*)d_in[1];
    float* out = (float*)d_out;
    (void)d_ws; (void)ws_size; (void)in_sizes; (void)n_in;

    (void)hipMemsetAsync(out, 0, (size_t)out_size * sizeof(float), stream);
    ska_fused<<<BATCH * CHAN * 4, 512, 0, stream>>>(x, w, out);
}